// Round 3
// baseline (288.036 us; speedup 1.0000x reference)
//
#include <hip/hip_runtime.h>

// Conv2d 5x5, C=3, O=1, stride 1, pad 2, N=256, H=W=224, +bias.
// R3: cooperative LDS-staged tiles (fixes R2's scratch-spill: WRITE was 7.6x
// ideal; and R0's latency-bound 10% BW: staging gives batched coalesced MLP).
//   - block 256 = (16,16); output tile 64x32; thread tile 4x2
//   - per-channel input tile 36x68 f32 in LDS (stride 76 dw, 16B-aligned rows)
//   - channel loop: issue ch c+1 global loads EARLY, compute c from LDS,
//     barrier, LDS-write c+1, barrier (loads hide under FMAs)
//   - weights reloaded per channel (25 uniform s_loads live at a time; the
//     75-at-once version blew the SGPR file and spilled in R2)
// Budgets: HBM 205+51 MB -> 41 us floor; LDS ~1 GB -> ~20 us; VALU ~18 us.

namespace {

constexpr int Hc = 224, Wc = 224, Cc = 3;
constexpr int HW = Hc * Wc;
constexpr int CHW = Cc * HW;
constexpr int BX = 16, BY = 16;          // 256 threads
constexpr int TX = 4, TY = 2;            // per-thread outputs
constexpr int TILE_X = BX * TX;          // 64
constexpr int TILE_Y = BY * TY;          // 32
constexpr int IN_X = TILE_X + 4;         // 68
constexpr int IN_Y = TILE_Y + 4;         // 36
constexpr int LDSW = 76;                 // row stride in dwords (padded, 16B-mult)
constexpr int CH2 = IN_X / 2;            // 34 float2 chunks per row
constexpr int CHUNKS = IN_Y * CH2;       // 1224
constexpr int NITER = (CHUNKS + BX * BY - 1) / (BX * BY);  // 5

__global__ __launch_bounds__(256, 6) void conv5x5_lds(
    const float* __restrict__ x, const float* __restrict__ wl,
    const float* __restrict__ bptr, float* __restrict__ out) {
  __shared__ float sm[IN_Y][LDSW];

  const int tid = threadIdx.y * BX + threadIdx.x;
  const int n = blockIdx.z;
  const int x0 = blockIdx.x * TILE_X;
  const int y0 = blockIdx.y * TILE_Y;

  const float* __restrict__ xn = x + (size_t)n * CHW;
  const float bias = bptr[0];

  float acc[TY][TX];
#pragma unroll
  for (int i = 0; i < TY; ++i)
#pragma unroll
    for (int j = 0; j < TX; ++j) acc[i][j] = 0.0f;

  // Staged values in flight (global -> reg -> LDS). All indices compile-time.
  float2 st[NITER];

  // ---- stage helpers (macros keep everything fully unrolled / in regs) ----
#define STAGE_LOAD(c)                                                         \
  do {                                                                        \
    const float* xc_ = xn + (c) * HW;                                         \
    _Pragma("unroll") for (int k_ = 0; k_ < NITER; ++k_) {                    \
      const int idx_ = tid + k_ * (BX * BY);                                  \
      float2 v_ = make_float2(0.f, 0.f);                                      \
      if (idx_ < CHUNKS) {                                                    \
        const int r_ = idx_ / CH2;                                            \
        const int ch_ = idx_ % CH2;                                           \
        const int gy_ = y0 - 2 + r_;                                          \
        const int gx_ = x0 - 2 + ch_ * 2;                                     \
        if (gy_ >= 0 && gy_ < Hc && gx_ >= 0 && gx_ < Wc)                     \
          v_ = *(const float2*)(xc_ + (size_t)gy_ * Wc + gx_);                \
      }                                                                       \
      st[k_] = v_;                                                            \
    }                                                                         \
  } while (0)

#define STAGE_WRITE()                                                         \
  do {                                                                        \
    _Pragma("unroll") for (int k_ = 0; k_ < NITER; ++k_) {                    \
      const int idx_ = tid + k_ * (BX * BY);                                  \
      if (idx_ < CHUNKS) {                                                    \
        const int r_ = idx_ / CH2;                                            \
        const int ch_ = idx_ % CH2;                                           \
        *(float2*)&sm[r_][ch_ * 2] = st[k_];                                  \
      }                                                                       \
    }                                                                         \
  } while (0)

  // Compute channel c from LDS. Weights: 25 wave-uniform loads -> SGPRs,
  // live only within this channel (avoids R2's 75-wide SGPR blowout).
#define COMPUTE(c)                                                            \
  do {                                                                        \
    float wc_[25];                                                            \
    _Pragma("unroll") for (int i_ = 0; i_ < 25; ++i_)                         \
        wc_[i_] = wl[(c) * 25 + i_];                                          \
    const int ly_ = threadIdx.y * TY;                                         \
    const int lx_ = threadIdx.x * TX;                                         \
    _Pragma("unroll") for (int iy_ = 0; iy_ < TY + 4; ++iy_) {                \
      const float4 a_ = *(const float4*)&sm[ly_ + iy_][lx_];                  \
      const float4 b_ = *(const float4*)&sm[ly_ + iy_][lx_ + 4];              \
      const float win_[8] = {a_.x, a_.y, a_.z, a_.w, b_.x, b_.y, b_.z, b_.w}; \
      _Pragma("unroll") for (int ky_ = 0; ky_ < 5; ++ky_) {                   \
        const int oy_ = iy_ - ky_;                                            \
        if (oy_ < 0 || oy_ >= TY) continue;                                   \
        _Pragma("unroll") for (int ox_ = 0; ox_ < TX; ++ox_) {                \
          _Pragma("unroll") for (int kx_ = 0; kx_ < 5; ++kx_) {               \
            acc[oy_][ox_] =                                                   \
                fmaf(win_[ox_ + kx_], wc_[ky_ * 5 + kx_], acc[oy_][ox_]);     \
          }                                                                   \
        }                                                                     \
      }                                                                       \
    }                                                                         \
  } while (0)

  // ---- pipeline: load(c+1) early, compute(c), then commit LDS(c+1) ----
  STAGE_LOAD(0);
  STAGE_WRITE();
  __syncthreads();

  STAGE_LOAD(1);        // in flight under compute(0)
  COMPUTE(0);
  __syncthreads();      // everyone done reading sm
  STAGE_WRITE();
  __syncthreads();

  STAGE_LOAD(2);        // in flight under compute(1)
  COMPUTE(1);
  __syncthreads();
  STAGE_WRITE();
  __syncthreads();

  COMPUTE(2);

#undef STAGE_LOAD
#undef STAGE_WRITE
#undef COMPUTE

  // ---- epilogue: bias + store (float4, 16B-aligned; x-guard for block 3) ----
  const int gx = x0 + threadIdx.x * TX;
  if (gx < Wc) {                           // gx mult of 4; gx<224 => gx<=220
    float* ob = out + (size_t)n * HW;
#pragma unroll
    for (int oy = 0; oy < TY; ++oy) {
      const int gy = y0 + threadIdx.y * TY + oy;   // always < 224
      float4 o;
      o.x = acc[oy][0] + bias;
      o.y = acc[oy][1] + bias;
      o.z = acc[oy][2] + bias;
      o.w = acc[oy][3] + bias;
      *(float4*)(ob + (size_t)gy * Wc + gx) = o;
    }
  }
}

}  // namespace

extern "C" void kernel_launch(void* const* d_in, const int* in_sizes, int n_in,
                              void* d_out, int out_size, void* d_ws, size_t ws_size,
                              hipStream_t stream) {
  const float* x  = (const float*)d_in[0];   // [N,3,224,224] f32
  const float* wl = (const float*)d_in[1];   // [1,75] f32
  const float* b  = (const float*)d_in[2];   // [1] f32
  float* out = (float*)d_out;                // [N,224,224] f32

  const int N = out_size / HW;               // 256

  dim3 block(BX, BY, 1);
  dim3 grid((Wc + TILE_X - 1) / TILE_X,      // 4
            (Hc + TILE_Y - 1) / TILE_Y,      // 7
            N);                              // 256
  conv5x5_lds<<<grid, block, 0, stream>>>(x, wl, b, out);
}

// Round 4
// 70.885 us; speedup vs baseline: 4.0634x; 4.0634x over previous
//
#include <hip/hip_runtime.h>

// Conv2d 5x5, C=3, O=1, stride 1, pad 2, N=256, H=W=224, +bias.
// R4 = R2's rolling-accumulator walker MINUS the launch_bounds min-waves arg.
// Post-mortem R2/R3: __launch_bounds__(256,6) forced VGPR_Count=40 -> massive
// scratch spills (WRITE_SIZE 392/652 MB vs 51 ideal). R0 (no min-arg) was
// spill-free at VGPR=104. So: let the allocator breathe.
// Also SY 16->8: grid now 12.5K waves (~49/CU of work) so residency, not the
// grid, bounds occupancy. Halo rows overlap between adjacent strips -> L2.
//   - thread owns a float2-wide output column, walks SY=8 rows
//   - 5-deep register accumulator ring; per step 9 independent 8B loads,
//     150 FMAs; explicit next-row prefetch + unroll 2 => ~18 loads in flight
//   - loads/output = 3 floats; HBM ideal 156+51 MB -> 33 us floor

namespace {

constexpr int Hc = 224, Wc = 224, Cc = 3;
constexpr int HW = Hc * Wc;
constexpr int CHW = Cc * HW;
constexpr int TXv = 2;              // outputs per thread in x (float2)
constexpr int NCOL = Wc / TXv;      // 112
constexpr int SY = 8;               // strip height per thread
constexpr int NSTRIP = Hc / SY;     // 28
constexpr int BLK = 256;

#define LOADROW(yi, dst)                                                      \
  do {                                                                        \
    if ((yi) >= 0 && (yi) < Hc) {                                             \
      const float* p_ = xb + (size_t)(yi) * Wc;                               \
      _Pragma("unroll") for (int c_ = 0; c_ < Cc; ++c_) {                     \
        const float* pc_ = p_ + c_ * HW;                                      \
        dst[c_][0] = *(const float2*)(pc_ + dA);                              \
        dst[c_][1] = *(const float2*)(pc_);                                   \
        dst[c_][2] = *(const float2*)(pc_ + dC);                              \
      }                                                                       \
    } else {                                                                  \
      _Pragma("unroll") for (int c_ = 0; c_ < Cc; ++c_) {                     \
        dst[c_][0] = make_float2(0.f, 0.f);                                   \
        dst[c_][1] = make_float2(0.f, 0.f);                                   \
        dst[c_][2] = make_float2(0.f, 0.f);                                   \
      }                                                                       \
    }                                                                         \
  } while (0)

// Accumulate one input row into the 5-deep ring. acc_k's output row takes
// vertical tap ky = 4-k from this input row.
#define ACCUM(buf)                                                            \
  do {                                                                        \
    _Pragma("unroll") for (int c_ = 0; c_ < Cc; ++c_) {                       \
      float win[6];                                                           \
      win[0] = lo ? 0.f : buf[c_][0].x;                                       \
      win[1] = lo ? 0.f : buf[c_][0].y;                                       \
      win[2] = buf[c_][1].x;                                                  \
      win[3] = buf[c_][1].y;                                                  \
      win[4] = hi ? 0.f : buf[c_][2].x;                                       \
      win[5] = hi ? 0.f : buf[c_][2].y;                                       \
      _Pragma("unroll") for (int kx_ = 0; kx_ < 5; ++kx_) {                   \
        acc0.x = fmaf(win[kx_], w[c_][4][kx_], acc0.x);                       \
        acc0.y = fmaf(win[kx_ + 1], w[c_][4][kx_], acc0.y);                   \
        acc1.x = fmaf(win[kx_], w[c_][3][kx_], acc1.x);                       \
        acc1.y = fmaf(win[kx_ + 1], w[c_][3][kx_], acc1.y);                   \
        acc2.x = fmaf(win[kx_], w[c_][2][kx_], acc2.x);                       \
        acc2.y = fmaf(win[kx_ + 1], w[c_][2][kx_], acc2.y);                   \
        acc3.x = fmaf(win[kx_], w[c_][1][kx_], acc3.x);                       \
        acc3.y = fmaf(win[kx_ + 1], w[c_][1][kx_], acc3.y);                   \
        acc4.x = fmaf(win[kx_], w[c_][0][kx_], acc4.x);                       \
        acc4.y = fmaf(win[kx_ + 1], w[c_][0][kx_], acc4.y);                   \
      }                                                                       \
    }                                                                         \
  } while (0)

__global__ __launch_bounds__(BLK) void conv5x5_roll(
    const float* __restrict__ x, const float* __restrict__ wl,
    const float* __restrict__ bptr, float* __restrict__ out) {
  const int t = blockIdx.x * BLK + threadIdx.x;
  // decode: col fastest (coalescing), then strip, then n
  const int col = t % NCOL;
  const int rest = t / NCOL;
  const int strip = rest % NSTRIP;
  const int n = rest / NSTRIP;

  const int x0 = col * TXv;
  const int y0 = strip * SY;
  const bool lo = (x0 == 0);            // left image edge
  const bool hi = (x0 == Wc - TXv);     // right image edge

  // Weights: wave-uniform, compile-time offsets -> s_load (SGPRs).
  float w[Cc][5][5];
#pragma unroll
  for (int c = 0; c < Cc; ++c)
#pragma unroll
    for (int i = 0; i < 25; ++i) w[c][i / 5][i % 5] = wl[c * 25 + i];
  const float bias = bptr[0];

  const float* xb = x + (size_t)n * CHW + x0;
  float* ob = out + (size_t)n * HW + x0;

  // Aligned 8B loads at x0-2/x0/x0+2; edge lanes redirect the fully-masked
  // load inward (values zeroed in ACCUM) -> zero OOB accesses.
  const int dA = lo ? 0 : -2;
  const int dC = hi ? 0 : 2;

  float2 cur[Cc][3], nxt[Cc][3];
  float2 acc0 = {0.f, 0.f}, acc1 = {0.f, 0.f}, acc2 = {0.f, 0.f},
         acc3 = {0.f, 0.f}, acc4 = {0.f, 0.f};

  LOADROW(y0 - 2, cur);

#pragma unroll 2
  for (int yi = y0 - 2; yi < y0 + SY + 2; ++yi) {
    LOADROW(yi + 1, nxt);   // prefetch next row while accumulating current
    ACCUM(cur);
    if (yi >= y0 + 2) {     // output row yi-2 is complete
      float2 o;
      o.x = acc0.x + bias;
      o.y = acc0.y + bias;
      *(float2*)(ob + (size_t)(yi - 2) * Wc) = o;
    }
    acc0 = acc1; acc1 = acc2; acc2 = acc3; acc3 = acc4;
    acc4 = make_float2(0.f, 0.f);
#pragma unroll
    for (int c = 0; c < Cc; ++c) {
      cur[c][0] = nxt[c][0];
      cur[c][1] = nxt[c][1];
      cur[c][2] = nxt[c][2];
    }
  }
}

}  // namespace

extern "C" void kernel_launch(void* const* d_in, const int* in_sizes, int n_in,
                              void* d_out, int out_size, void* d_ws, size_t ws_size,
                              hipStream_t stream) {
  const float* x  = (const float*)d_in[0];   // [N,3,224,224] f32
  const float* wl = (const float*)d_in[1];   // [1,75] f32
  const float* b  = (const float*)d_in[2];   // [1] f32
  float* out = (float*)d_out;                // [N,224,224] f32

  const int N = out_size / HW;               // 256
  const int total = N * NSTRIP * NCOL;       // 802816
  const int nblk = total / BLK;              // 3136

  conv5x5_roll<<<nblk, BLK, 0, stream>>>(x, wl, b, out);
}